// Round 3
// baseline (309.696 us; speedup 1.0000x reference)
//
#include <hip/hip_runtime.h>

typedef __bf16 bf16;
typedef __attribute__((ext_vector_type(4))) __bf16 bf16x4;
typedef __attribute__((ext_vector_type(8))) __bf16 bf16x8;
typedef __attribute__((ext_vector_type(4))) float f32x4;

__device__ __forceinline__ void gload_lds16(const void* g, void* l) {
  __builtin_amdgcn_global_load_lds(
      (const __attribute__((address_space(1))) unsigned int*)(unsigned long long)g,
      (__attribute__((address_space(3))) unsigned int*)(unsigned long long)l,
      16, 0, 0);
}

// ---------------- cast fp32 -> bf16 (x4 vectorized) ----------------
__global__ void cast_f32_bf16(const float* __restrict__ in, bf16* __restrict__ out, int n4) {
  int i = blockIdx.x * blockDim.x + threadIdx.x;
  if (i >= n4) return;
  float4 v = reinterpret_cast<const float4*>(in)[i];
  bf16x4 o;
  o[0] = (bf16)v.x; o[1] = (bf16)v.y; o[2] = (bf16)v.z; o[3] = (bf16)v.w;
  reinterpret_cast<bf16x4*>(out)[i] = o;
}

// ------- transpose+cast: V (rows x cols, f32) -> VT (cols x rows, bf16), batched -------
__global__ void transpose_cast(const float* __restrict__ V, bf16* __restrict__ VT,
                               int rows, int cols) {
  __shared__ bf16 tile[64][65];
  const int b = blockIdx.z;
  const float* Vb = V + (long)b * rows * cols;
  bf16* VTb = VT + (long)b * rows * cols;
  const int d0 = blockIdx.x * 64;
  const int k0 = blockIdx.y * 64;
  const int t = threadIdx.x;
  const int r = t >> 4;
  const int c4 = (t & 15) * 4;
#pragma unroll
  for (int p = 0; p < 4; ++p) {
    float4 v = *reinterpret_cast<const float4*>(&Vb[(long)(k0 + p * 16 + r) * cols + d0 + c4]);
    tile[p * 16 + r][c4 + 0] = (bf16)v.x;
    tile[p * 16 + r][c4 + 1] = (bf16)v.y;
    tile[p * 16 + r][c4 + 2] = (bf16)v.z;
    tile[p * 16 + r][c4 + 3] = (bf16)v.w;
  }
  __syncthreads();
#pragma unroll
  for (int p = 0; p < 4; ++p) {
    const int dd = p * 16 + r;
    bf16x4 o;
    o[0] = tile[c4 + 0][dd];
    o[1] = tile[c4 + 1][dd];
    o[2] = tile[c4 + 2][dd];
    o[3] = tile[c4 + 3][dd];
    *reinterpret_cast<bf16x4*>(&VTb[(long)(d0 + dd) * rows + k0 + c4]) = o;
  }
}

// ---------------- in-place row softmax, row length 2048, bf16 ----------------
__global__ void softmax_rows(bf16* __restrict__ S) {
  const long row = blockIdx.x;
  bf16* p = S + row * 2048;
  const int t = threadIdx.x;
  const int wid = t >> 6;
  const int lane = t & 63;
  bf16x8 v = *reinterpret_cast<bf16x8*>(p + t * 8);
  float f[8];
  float m = -3.0e38f;
#pragma unroll
  for (int j = 0; j < 8; ++j) { f[j] = (float)v[j]; m = fmaxf(m, f[j]); }
#pragma unroll
  for (int off = 32; off >= 1; off >>= 1) m = fmaxf(m, __shfl_xor(m, off));
  __shared__ float redm[4], reds[4];
  if (lane == 0) redm[wid] = m;
  __syncthreads();
  m = fmaxf(fmaxf(redm[0], redm[1]), fmaxf(redm[2], redm[3]));
  float s = 0.f;
#pragma unroll
  for (int j = 0; j < 8; ++j) { f[j] = __expf(f[j] - m); s += f[j]; }
#pragma unroll
  for (int off = 32; off >= 1; off >>= 1) s += __shfl_xor(s, off);
  if (lane == 0) reds[wid] = s;
  __syncthreads();
  s = reds[0] + reds[1] + reds[2] + reds[3];
  const float inv = 1.0f / s;
  bf16x8 o;
#pragma unroll
  for (int j = 0; j < 8; ++j) o[j] = (bf16)(f[j] * inv);
  *reinterpret_cast<bf16x8*>(p + t * 8) = o;
}

// ---------------- B^T GEMM, 256x256 tile, BK=64, counted-vmcnt 4-phase schedule --------
// 512 threads = 8 waves (2 M x 4 N); wave owns 128x64 output (8x4 frags, acc[8][4]).
// LDS: 8 half-tiles of [256 rows][32 k] bf16 (16 KB each) = 128 KiB:
//   index [buf][op][khalf]; half-tile = one MFMA k-slice (k 0-31 / 32-63) of one operand.
//   64 B row pitch => per-column ds_read_b128 is bank-uniform (no swizzle needed);
//   linear global_load_lds dest == row-major layout; source 64 B/row coalesced.
// Per K-tile, 4 phases (kh, mq): {ds_read k-half frags | stage 1 half-tile of kt+1 ->
//   [vmcnt(4) at P1/P3 only] -> s_barrier -> lgkmcnt(0) -> setprio(1) 16 MFMA setprio(0)
//   -> s_barrier}. vmcnt(4) drains exactly the 2 half-tiles the next phase-pair reads,
//   keeping 4 loads in flight across the tile boundary (never vmcnt(0) in the loop).
// MODE 0: bf16 out + bias; MODE 1: bf16 out * (1/scale); MODE 2: f32 out.

#define BARRIER __builtin_amdgcn_s_barrier()
#define LGKM0                                              \
  do {                                                     \
    asm volatile("s_waitcnt lgkmcnt(0)" ::: "memory");     \
    __builtin_amdgcn_sched_barrier(0);                     \
  } while (0)
#define VM4                                                \
  do {                                                     \
    asm volatile("s_waitcnt vmcnt(4)" ::: "memory");       \
    __builtin_amdgcn_sched_barrier(0);                     \
  } while (0)
#define VM0                                                \
  do {                                                     \
    asm volatile("s_waitcnt vmcnt(0)" ::: "memory");       \
    __builtin_amdgcn_sched_barrier(0);                     \
  } while (0)

// stage one half-tile (op, khalf) of the tile at global k-offset into buf:
// 2 global_load_lds per wave (rows 0-127 then 128-255 of the 256-row panel).
#define STAGE(buf, op, kh, g_)                                  \
  {                                                             \
    bf16* l_ = ldsw + (((buf) * 2 + (op)) * 2 + (kh)) * 8192;   \
    gload_lds16((g_), l_);                                      \
    gload_lds16((g_) + rK128, l_ + 4096);                       \
  }

#define LOADA(buf, kh, mq)                                                     \
  _Pragma("unroll") for (int m_ = 0; m_ < 4; ++m_)                             \
      a[m_] = *reinterpret_cast<const bf16x8*>(                                \
          aB + ((buf) * 4 + (kh)) * 8192 + (mq) * 2048 + m_ * 512);
#define LOADB(buf, kh)                                                         \
  _Pragma("unroll") for (int n_ = 0; n_ < 4; ++n_)                             \
      b[n_] = *reinterpret_cast<const bf16x8*>(                                \
          bB + ((buf) * 4 + 2 + (kh)) * 8192 + n_ * 512);

#define MFMAP(mq)                                                              \
  _Pragma("unroll") for (int m_ = 0; m_ < 4; ++m_)                             \
  _Pragma("unroll") for (int n_ = 0; n_ < 4; ++n_)                             \
      acc[(mq) * 4 + m_][n_] = __builtin_amdgcn_mfma_f32_16x16x32_bf16(        \
          a[m_], b[n_], acc[(mq) * 4 + m_][n_], 0, 0, 0);

template <int MODE>
__global__ __launch_bounds__(512, 2)
void gemm_bt(const bf16* __restrict__ A, const bf16* __restrict__ Bm,
             const float* __restrict__ bias, void* __restrict__ Cvoid,
             const int* __restrict__ scale_ptr,
             int M, int N, int K, long sA, long sB, long sC) {
  __shared__ bf16 lds[8][256][32];  // [buf*4+op*2+kh][row][32k] = 128 KiB
  const int t = threadIdx.x;
  const int lane = t & 63;
  const int wid = t >> 6;   // 0..7
  const int wm = wid >> 2;  // 0..1
  const int wn = wid & 3;   // 0..3
  (void)M;

  // XCD-aware bijective swizzle (all grids here have nwg % 8 == 0)
  const int gx = gridDim.x, gy = gridDim.y;
  const int nwg = gx * gy * gridDim.z;
  int id = blockIdx.x + gx * (blockIdx.y + gy * blockIdx.z);
  {
    const int cpx = nwg >> 3;
    id = (id & 7) * cpx + (id >> 3);
  }
  const int bx = id % gx;
  const int by = (id / gx) % gy;
  const int bz = id / (gx * gy);

  const bf16* Ab = A + (long)bz * sA;
  const bf16* Bb = Bm + (long)bz * sB;
  const int tile_m = by * 256;
  const int tile_n = bx * 256;

  // staging: half-tile = [256][32] = 1024 x 16B chunks (4 per row); thread t covers
  // chunk t (row=t>>2, kc=t&3) and chunk t+512 (row+128). Dest linear == row-major.
  const int srow = t >> 2;           // 0..127
  const int soff = (t & 3) * 8;      // elem offset within 32-elem row
  const bf16* gA = Ab + (long)(tile_m + srow) * K + soff;
  const bf16* gB = Bb + (long)(tile_n + srow) * K + soff;
  const long rK128 = (long)K << 7;   // +128 rows
  bf16* const ldsw = &lds[0][0][0] + wid * 512;  // wave-uniform dest (+HW lane*16B)

  // fragment reads: row = (sub-tile base) + frow, k elems fko..fko+7 within the k-half
  const int frow = lane & 15;
  const int fko = (lane >> 4) * 8;
  const bf16* aB = &lds[0][0][0] + (wm * 128 + frow) * 32 + fko;
  const bf16* bB = &lds[0][0][0] + (wn * 64 + frow) * 32 + fko;

  bf16x8 a[4], b[4];
  f32x4 acc[8][4] = {};

  // prologue: stage tile 0 (4 half-tiles, 8 loads/wave), wait for its H0 pair only
  STAGE(0, 0, 0, gA)
  STAGE(0, 1, 0, gB)
  STAGE(0, 0, 1, gA + 32)
  STAGE(0, 1, 1, gB + 32)
  VM4;
  BARRIER;

  const int NK = K >> 6;
  int c = 0;
  for (int kt = 0; kt < NK - 1; ++kt, c ^= 1) {
    const long ko = (long)(kt + 1) << 6;
    // P0: (kh0, mq0); stage A.H0(kt+1)
    LOADB(c, 0)
    LOADA(c, 0, 0)
    STAGE(c ^ 1, 0, 0, gA + ko)
    BARRIER;
    LGKM0;
    __builtin_amdgcn_s_setprio(1);
    MFMAP(0)
    __builtin_amdgcn_s_setprio(0);
    BARRIER;
    // P1: (kh0, mq1); stage B.H0(kt+1); drain H1(kt) pair
    LOADA(c, 0, 1)
    STAGE(c ^ 1, 1, 0, gB + ko)
    VM4;
    BARRIER;
    LGKM0;
    __builtin_amdgcn_s_setprio(1);
    MFMAP(1)
    __builtin_amdgcn_s_setprio(0);
    BARRIER;
    // P2: (kh1, mq0); stage A.H1(kt+1)
    LOADB(c, 1)
    LOADA(c, 1, 0)
    STAGE(c ^ 1, 0, 1, gA + ko + 32)
    BARRIER;
    LGKM0;
    __builtin_amdgcn_s_setprio(1);
    MFMAP(0)
    __builtin_amdgcn_s_setprio(0);
    BARRIER;
    // P3: (kh1, mq1); stage B.H1(kt+1); drain H0(kt+1) pair for next tile's P0
    LOADA(c, 1, 1)
    STAGE(c ^ 1, 1, 1, gB + ko + 32)
    VM4;
    BARRIER;
    LGKM0;
    __builtin_amdgcn_s_setprio(1);
    MFMAP(1)
    __builtin_amdgcn_s_setprio(0);
    BARRIER;
  }
  // peeled last tile: H0 pair already drained+barrier'd by final P3
  LOADB(c, 0)
  LOADA(c, 0, 0)
  LGKM0;
  MFMAP(0)
  LOADA(c, 0, 1)
  LGKM0;
  MFMAP(1)
  VM0;        // drain H1 pair
  BARRIER;
  LOADB(c, 1)
  LOADA(c, 1, 0)
  LGKM0;
  MFMAP(0)
  LOADA(c, 1, 1)
  LGKM0;
  MFMAP(1)

  float scl = 1.0f;
  if (MODE == 1) {
    const int iv = scale_ptr[0];
    const float fv = __int_as_float(iv);
    const float sv = (iv > 0 && iv < (1 << 20)) ? (float)iv : fv;
    scl = 1.0f / sv;
  }
  // C/D layout (verified m89/m91): col=lane&15, row=(lane>>4)*4+reg
  const int rb = tile_m + wm * 128 + ((lane >> 4) << 2);
  const int cb = tile_n + wn * 64 + (lane & 15);
  if (MODE == 2) {
    float* C = reinterpret_cast<float*>(Cvoid) + (long)bz * sC;
#pragma unroll
    for (int mf = 0; mf < 8; ++mf)
#pragma unroll
      for (int nf = 0; nf < 4; ++nf)
#pragma unroll
        for (int r = 0; r < 4; ++r)
          C[(long)(rb + mf * 16 + r) * N + (cb + nf * 16)] = acc[mf][nf][r];
  } else {
    bf16* C = reinterpret_cast<bf16*>(Cvoid) + (long)bz * sC;
#pragma unroll
    for (int nf = 0; nf < 4; ++nf) {
      const int col = cb + nf * 16;
      const float bv = (MODE == 0) ? bias[col] : 0.0f;
#pragma unroll
      for (int mf = 0; mf < 8; ++mf)
#pragma unroll
        for (int r = 0; r < 4; ++r)
          C[(long)(rb + mf * 16 + r) * N + col] = (bf16)(acc[mf][nf][r] * scl + bv);
    }
  }
}

extern "C" void kernel_launch(void* const* d_in, const int* in_sizes, int n_in,
                              void* d_out, int out_size, void* d_ws, size_t ws_size,
                              hipStream_t stream) {
  (void)in_sizes; (void)n_in; (void)out_size; (void)ws_size;
  const float* query = (const float*)d_in[0];
  const float* key   = (const float*)d_in[1];
  const float* value = (const float*)d_in[2];
  const float* Wq    = (const float*)d_in[3];
  const float* bq    = (const float*)d_in[4];
  const float* Wk    = (const float*)d_in[5];
  const float* bk    = (const float*)d_in[6];
  const int*   scale = (const int*)d_in[7];

  const int L = 2048, D = 1024;
  // ws layout (bytes):
  //   [0,   64M): q_cast(32M) + k_cast(32M), later reused as S/P (8*2048*2048 bf16 = 64M exactly)
  //   [64M, 96M): Qp   [96M,128M): Kp   [128M,160M): VT   [160M,162M): Wq_b  [162M,164M): Wk_b
  char* ws = (char*)d_ws;
  bf16* q_cast = (bf16*)ws;
  bf16* k_cast = q_cast + (long)16384 * 1024;
  bf16* S      = q_cast;
  bf16* Qp     = (bf16*)(ws + (size_t)67108864);
  bf16* Kp     = (bf16*)(ws + (size_t)100663296);
  bf16* VT     = (bf16*)(ws + (size_t)134217728);
  bf16* Wqb    = (bf16*)(ws + (size_t)167772160);
  bf16* Wkb    = (bf16*)(ws + (size_t)169869312);

  cast_f32_bf16<<<16384, 256, 0, stream>>>(query, q_cast, 4194304);
  cast_f32_bf16<<<16384, 256, 0, stream>>>(key,   k_cast, 4194304);
  cast_f32_bf16<<<1024,  256, 0, stream>>>(Wq, Wqb, 262144);
  cast_f32_bf16<<<1024,  256, 0, stream>>>(Wk, Wkb, 262144);
  transpose_cast<<<dim3(16, 32, 8), 256, 0, stream>>>(value, VT, 2048, 1024);

  // projections: Qp = q_cast @ Wq^T + bq   (M=16384, N=1024, K=1024)
  gemm_bt<0><<<dim3(4, 64, 1), 512, 0, stream>>>(q_cast, Wqb, bq, Qp, nullptr,
                                                 16384, 1024, 1024, 0, 0, 0);
  gemm_bt<0><<<dim3(4, 64, 1), 512, 0, stream>>>(k_cast, Wkb, bk, Kp, nullptr,
                                                 16384, 1024, 1024, 0, 0, 0);
  // scores: S[b] = (Qp[b] @ Kp[b]^T) / scale   (M=N=2048, K=1024, batched over 8)
  gemm_bt<1><<<dim3(8, 8, 8), 512, 0, stream>>>(Qp, Kp, nullptr, S, scale,
                                                2048, 2048, 1024,
                                                (long)L * D, (long)L * D, (long)L * L);
  softmax_rows<<<16384, 256, 0, stream>>>(S);
  // out: O[b] = P[b] @ VT[b]^T  (M=2048, N=1024, K=2048, f32 out)
  gemm_bt<2><<<dim3(4, 8, 8), 512, 0, stream>>>(S, VT, nullptr, d_out, nullptr,
                                                2048, 1024, 2048,
                                                (long)L * L, (long)D * L, (long)L * D);
}

// Round 4
// 298.374 us; speedup vs baseline: 1.0379x; 1.0379x over previous
//
#include <hip/hip_runtime.h>

typedef __bf16 bf16;
typedef __attribute__((ext_vector_type(4))) __bf16 bf16x4;
typedef __attribute__((ext_vector_type(8))) __bf16 bf16x8;
typedef __attribute__((ext_vector_type(4))) float f32x4;

__device__ __forceinline__ void gload_lds16(const void* g, void* l) {
  __builtin_amdgcn_global_load_lds(
      (const __attribute__((address_space(1))) unsigned int*)(unsigned long long)g,
      (__attribute__((address_space(3))) unsigned int*)(unsigned long long)l,
      16, 0, 0);
}

// ---------------- cast fp32 -> bf16 (x4 vectorized) ----------------
__global__ void cast_f32_bf16(const float* __restrict__ in, bf16* __restrict__ out, int n4) {
  int i = blockIdx.x * blockDim.x + threadIdx.x;
  if (i >= n4) return;
  float4 v = reinterpret_cast<const float4*>(in)[i];
  bf16x4 o;
  o[0] = (bf16)v.x; o[1] = (bf16)v.y; o[2] = (bf16)v.z; o[3] = (bf16)v.w;
  reinterpret_cast<bf16x4*>(out)[i] = o;
}

// ------- transpose+cast: V (rows x cols, f32) -> VT (cols x rows, bf16), batched -------
__global__ void transpose_cast(const float* __restrict__ V, bf16* __restrict__ VT,
                               int rows, int cols) {
  __shared__ bf16 tile[64][65];
  const int b = blockIdx.z;
  const float* Vb = V + (long)b * rows * cols;
  bf16* VTb = VT + (long)b * rows * cols;
  const int d0 = blockIdx.x * 64;
  const int k0 = blockIdx.y * 64;
  const int t = threadIdx.x;
  const int r = t >> 4;
  const int c4 = (t & 15) * 4;
#pragma unroll
  for (int p = 0; p < 4; ++p) {
    float4 v = *reinterpret_cast<const float4*>(&Vb[(long)(k0 + p * 16 + r) * cols + d0 + c4]);
    tile[p * 16 + r][c4 + 0] = (bf16)v.x;
    tile[p * 16 + r][c4 + 1] = (bf16)v.y;
    tile[p * 16 + r][c4 + 2] = (bf16)v.z;
    tile[p * 16 + r][c4 + 3] = (bf16)v.w;
  }
  __syncthreads();
#pragma unroll
  for (int p = 0; p < 4; ++p) {
    const int dd = p * 16 + r;
    bf16x4 o;
    o[0] = tile[c4 + 0][dd];
    o[1] = tile[c4 + 1][dd];
    o[2] = tile[c4 + 2][dd];
    o[3] = tile[c4 + 3][dd];
    *reinterpret_cast<bf16x4*>(&VTb[(long)(d0 + dd) * rows + k0 + c4]) = o;
  }
}

// ---------------- in-place row softmax, row length 2048, bf16 ----------------
__global__ void softmax_rows(bf16* __restrict__ S) {
  const long row = blockIdx.x;
  bf16* p = S + row * 2048;
  const int t = threadIdx.x;
  const int wid = t >> 6;
  const int lane = t & 63;
  bf16x8 v = *reinterpret_cast<bf16x8*>(p + t * 8);
  float f[8];
  float m = -3.0e38f;
#pragma unroll
  for (int j = 0; j < 8; ++j) { f[j] = (float)v[j]; m = fmaxf(m, f[j]); }
#pragma unroll
  for (int off = 32; off >= 1; off >>= 1) m = fmaxf(m, __shfl_xor(m, off));
  __shared__ float redm[4], reds[4];
  if (lane == 0) redm[wid] = m;
  __syncthreads();
  m = fmaxf(fmaxf(redm[0], redm[1]), fmaxf(redm[2], redm[3]));
  float s = 0.f;
#pragma unroll
  for (int j = 0; j < 8; ++j) { f[j] = __expf(f[j] - m); s += f[j]; }
#pragma unroll
  for (int off = 32; off >= 1; off >>= 1) s += __shfl_xor(s, off);
  if (lane == 0) reds[wid] = s;
  __syncthreads();
  s = reds[0] + reds[1] + reds[2] + reds[3];
  const float inv = 1.0f / s;
  bf16x8 o;
#pragma unroll
  for (int j = 0; j < 8; ++j) o[j] = (bf16)(f[j] * inv);
  *reinterpret_cast<bf16x8*>(p + t * 8) = o;
}

// ---------------- B^T GEMM, 256x256 tile, BK=64, counted-vmcnt 4-phase schedule --------
// 512 threads = 8 waves (2 M x 4 N); wave owns 128x64 output (8x4 frags, acc[8][4]).
// LDS: 8 half-tiles of [256 rows][32 k] bf16 (16 KB each) = 128 KiB, [buf][op][kh].
// XOR chunk swizzle (R1-verified, 0 conflicts at identical 64B pitch + read pattern):
//   physical 16B-chunk = logical kc ^ ((row>>1)&3).
//   - read side: swizzle index depends only on frow=lane&15 (all row offsets are
//     multiples of 16) -> one lane-constant offset, ds_read_b128 spreads 16-lane
//     groups over all 8 bank-quads (2 lanes/bank).
//   - staging: source pre-swizzled within each 64B row (still coalesced); dest
//     linear (global_load_lds HW requirement); +128-row chunk keeps same swizzle.
// Per K-tile, 4 phases (kh, mq): {ds_read k-half frags | stage 1 half-tile of kt+1 ->
//   [vmcnt(4) at P1/P3 only] -> s_barrier -> lgkmcnt(0) -> setprio(1) 16 MFMA setprio(0)
//   -> s_barrier}. vmcnt(4) drains exactly the 2 half-tiles the next phase-pair reads,
//   keeping 4 loads in flight across the tile boundary (never vmcnt(0) in the loop).
// MODE 0: bf16 out + bias; MODE 1: bf16 out * (1/scale); MODE 2: f32 out.

#define BARRIER __builtin_amdgcn_s_barrier()
#define LGKM0                                              \
  do {                                                     \
    asm volatile("s_waitcnt lgkmcnt(0)" ::: "memory");     \
    __builtin_amdgcn_sched_barrier(0);                     \
  } while (0)
#define VM4                                                \
  do {                                                     \
    asm volatile("s_waitcnt vmcnt(4)" ::: "memory");       \
    __builtin_amdgcn_sched_barrier(0);                     \
  } while (0)
#define VM0                                                \
  do {                                                     \
    asm volatile("s_waitcnt vmcnt(0)" ::: "memory");       \
    __builtin_amdgcn_sched_barrier(0);                     \
  } while (0)

// stage one half-tile (op, khalf) of the tile at global k-offset into buf:
// 2 global_load_lds per wave (rows 0-127 then 128-255 of the 256-row panel).
#define STAGE(buf, op, kh, g_)                                  \
  {                                                             \
    bf16* l_ = ldsw + (((buf) * 2 + (op)) * 2 + (kh)) * 8192;   \
    gload_lds16((g_), l_);                                      \
    gload_lds16((g_) + rK128, l_ + 4096);                       \
  }

#define LOADA(buf, kh, mq)                                                     \
  _Pragma("unroll") for (int m_ = 0; m_ < 4; ++m_)                             \
      a[m_] = *reinterpret_cast<const bf16x8*>(                                \
          aB + ((buf) * 4 + (kh)) * 8192 + (mq) * 2048 + m_ * 512);
#define LOADB(buf, kh)                                                         \
  _Pragma("unroll") for (int n_ = 0; n_ < 4; ++n_)                             \
      b[n_] = *reinterpret_cast<const bf16x8*>(                                \
          bB + ((buf) * 4 + 2 + (kh)) * 8192 + n_ * 512);

#define MFMAP(mq)                                                              \
  _Pragma("unroll") for (int m_ = 0; m_ < 4; ++m_)                             \
  _Pragma("unroll") for (int n_ = 0; n_ < 4; ++n_)                             \
      acc[(mq) * 4 + m_][n_] = __builtin_amdgcn_mfma_f32_16x16x32_bf16(        \
          a[m_], b[n_], acc[(mq) * 4 + m_][n_], 0, 0, 0);

template <int MODE>
__global__ __launch_bounds__(512, 2)
void gemm_bt(const bf16* __restrict__ A, const bf16* __restrict__ Bm,
             const float* __restrict__ bias, void* __restrict__ Cvoid,
             const int* __restrict__ scale_ptr,
             int M, int N, int K, long sA, long sB, long sC) {
  __shared__ bf16 lds[8][256][32];  // [buf*4+op*2+kh][row][32k] = 128 KiB
  const int t = threadIdx.x;
  const int lane = t & 63;
  const int wid = t >> 6;   // 0..7
  const int wm = wid >> 2;  // 0..1
  const int wn = wid & 3;   // 0..3
  (void)M;

  // XCD-aware bijective swizzle (all grids here have nwg % 8 == 0)
  const int gx = gridDim.x, gy = gridDim.y;
  const int nwg = gx * gy * gridDim.z;
  int id = blockIdx.x + gx * (blockIdx.y + gy * blockIdx.z);
  {
    const int cpx = nwg >> 3;
    id = (id & 7) * cpx + (id >> 3);
  }
  const int bx = id % gx;
  const int by = (id / gx) % gy;
  const int bz = id / (gx * gy);

  const bf16* Ab = A + (long)bz * sA;
  const bf16* Bb = Bm + (long)bz * sB;
  const int tile_m = by * 256;
  const int tile_n = bx * 256;

  // staging: half-tile = [256][32] = 1024 x 16B chunks (4 per row); thread t covers
  // chunk t (row=t>>2, kc=t&3) and chunk t+512 (row+128: same swizzle, 128%4==0).
  // Source pre-swizzled: global kc = (t&3) ^ ((row>>1)&3). Dest linear.
  const int srow = t >> 2;                              // 0..127
  const int soff = (((t & 3) ^ ((t >> 3) & 3)) << 3);   // swizzled elem offset in row
  const bf16* gA = Ab + (long)(tile_m + srow) * K + soff;
  const bf16* gB = Bb + (long)(tile_n + srow) * K + soff;
  const long rK128 = (long)K << 7;   // +128 rows
  bf16* const ldsw = &lds[0][0][0] + wid * 512;  // wave-uniform dest (+HW lane*16B)

  // fragment reads: row = base + frow (base % 16 == 0), logical k-chunk lane>>4;
  // physical chunk = (lane>>4) ^ ((frow>>1)&3) -> lane-constant byte offset.
  const int frow = lane & 15;
  const int pko = (((lane >> 4) ^ ((lane >> 1) & 3)) << 3);
  const bf16* aB = &lds[0][0][0] + (wm * 128 + frow) * 32 + pko;
  const bf16* bB = &lds[0][0][0] + (wn * 64 + frow) * 32 + pko;

  bf16x8 a[4], b[4];
  f32x4 acc[8][4] = {};

  // prologue: stage tile 0 (4 half-tiles, 8 loads/wave), wait for its H0 pair only
  STAGE(0, 0, 0, gA)
  STAGE(0, 1, 0, gB)
  STAGE(0, 0, 1, gA + 32)
  STAGE(0, 1, 1, gB + 32)
  VM4;
  BARRIER;

  const int NK = K >> 6;
  int c = 0;
  for (int kt = 0; kt < NK - 1; ++kt, c ^= 1) {
    const long ko = (long)(kt + 1) << 6;
    // P0: (kh0, mq0); stage A.H0(kt+1)
    LOADB(c, 0)
    LOADA(c, 0, 0)
    STAGE(c ^ 1, 0, 0, gA + ko)
    BARRIER;
    LGKM0;
    __builtin_amdgcn_s_setprio(1);
    MFMAP(0)
    __builtin_amdgcn_s_setprio(0);
    BARRIER;
    // P1: (kh0, mq1); stage B.H0(kt+1); drain H1(kt) pair
    LOADA(c, 0, 1)
    STAGE(c ^ 1, 1, 0, gB + ko)
    VM4;
    BARRIER;
    LGKM0;
    __builtin_amdgcn_s_setprio(1);
    MFMAP(1)
    __builtin_amdgcn_s_setprio(0);
    BARRIER;
    // P2: (kh1, mq0); stage A.H1(kt+1)
    LOADB(c, 1)
    LOADA(c, 1, 0)
    STAGE(c ^ 1, 0, 1, gA + ko + 32)
    BARRIER;
    LGKM0;
    __builtin_amdgcn_s_setprio(1);
    MFMAP(0)
    __builtin_amdgcn_s_setprio(0);
    BARRIER;
    // P3: (kh1, mq1); stage B.H1(kt+1); drain H0(kt+1) pair for next tile's P0
    LOADA(c, 1, 1)
    STAGE(c ^ 1, 1, 1, gB + ko + 32)
    VM4;
    BARRIER;
    LGKM0;
    __builtin_amdgcn_s_setprio(1);
    MFMAP(1)
    __builtin_amdgcn_s_setprio(0);
    BARRIER;
  }
  // peeled last tile: H0 pair already drained+barrier'd by final P3
  LOADB(c, 0)
  LOADA(c, 0, 0)
  LGKM0;
  MFMAP(0)
  LOADA(c, 0, 1)
  LGKM0;
  MFMAP(1)
  VM0;        // drain H1 pair
  BARRIER;
  LOADB(c, 1)
  LOADA(c, 1, 0)
  LGKM0;
  MFMAP(0)
  LOADA(c, 1, 1)
  LGKM0;
  MFMAP(1)

  float scl = 1.0f;
  if (MODE == 1) {
    const int iv = scale_ptr[0];
    const float fv = __int_as_float(iv);
    const float sv = (iv > 0 && iv < (1 << 20)) ? (float)iv : fv;
    scl = 1.0f / sv;
  }
  // C/D layout (verified m89/m91): col=lane&15, row=(lane>>4)*4+reg
  const int rb = tile_m + wm * 128 + ((lane >> 4) << 2);
  const int cb = tile_n + wn * 64 + (lane & 15);
  if (MODE == 2) {
    float* C = reinterpret_cast<float*>(Cvoid) + (long)bz * sC;
#pragma unroll
    for (int mf = 0; mf < 8; ++mf)
#pragma unroll
      for (int nf = 0; nf < 4; ++nf)
#pragma unroll
        for (int r = 0; r < 4; ++r)
          C[(long)(rb + mf * 16 + r) * N + (cb + nf * 16)] = acc[mf][nf][r];
  } else {
    bf16* C = reinterpret_cast<bf16*>(Cvoid) + (long)bz * sC;
#pragma unroll
    for (int nf = 0; nf < 4; ++nf) {
      const int col = cb + nf * 16;
      const float bv = (MODE == 0) ? bias[col] : 0.0f;
#pragma unroll
      for (int mf = 0; mf < 8; ++mf)
#pragma unroll
        for (int r = 0; r < 4; ++r)
          C[(long)(rb + mf * 16 + r) * N + col] = (bf16)(acc[mf][nf][r] * scl + bv);
    }
  }
}

extern "C" void kernel_launch(void* const* d_in, const int* in_sizes, int n_in,
                              void* d_out, int out_size, void* d_ws, size_t ws_size,
                              hipStream_t stream) {
  (void)in_sizes; (void)n_in; (void)out_size; (void)ws_size;
  const float* query = (const float*)d_in[0];
  const float* key   = (const float*)d_in[1];
  const float* value = (const float*)d_in[2];
  const float* Wq    = (const float*)d_in[3];
  const float* bq    = (const float*)d_in[4];
  const float* Wk    = (const float*)d_in[5];
  const float* bk    = (const float*)d_in[6];
  const int*   scale = (const int*)d_in[7];

  const int L = 2048, D = 1024;
  // ws layout (bytes):
  //   [0,   64M): q_cast(32M) + k_cast(32M), later reused as S/P (8*2048*2048 bf16 = 64M exactly)
  //   [64M, 96M): Qp   [96M,128M): Kp   [128M,160M): VT   [160M,162M): Wq_b  [162M,164M): Wk_b
  char* ws = (char*)d_ws;
  bf16* q_cast = (bf16*)ws;
  bf16* k_cast = q_cast + (long)16384 * 1024;
  bf16* S      = q_cast;
  bf16* Qp     = (bf16*)(ws + (size_t)67108864);
  bf16* Kp     = (bf16*)(ws + (size_t)100663296);
  bf16* VT     = (bf16*)(ws + (size_t)134217728);
  bf16* Wqb    = (bf16*)(ws + (size_t)167772160);
  bf16* Wkb    = (bf16*)(ws + (size_t)169869312);

  cast_f32_bf16<<<16384, 256, 0, stream>>>(query, q_cast, 4194304);
  cast_f32_bf16<<<16384, 256, 0, stream>>>(key,   k_cast, 4194304);
  cast_f32_bf16<<<1024,  256, 0, stream>>>(Wq, Wqb, 262144);
  cast_f32_bf16<<<1024,  256, 0, stream>>>(Wk, Wkb, 262144);
  transpose_cast<<<dim3(16, 32, 8), 256, 0, stream>>>(value, VT, 2048, 1024);

  // projections: Qp = q_cast @ Wq^T + bq   (M=16384, N=1024, K=1024)
  gemm_bt<0><<<dim3(4, 64, 1), 512, 0, stream>>>(q_cast, Wqb, bq, Qp, nullptr,
                                                 16384, 1024, 1024, 0, 0, 0);
  gemm_bt<0><<<dim3(4, 64, 1), 512, 0, stream>>>(k_cast, Wkb, bk, Kp, nullptr,
                                                 16384, 1024, 1024, 0, 0, 0);
  // scores: S[b] = (Qp[b] @ Kp[b]^T) / scale   (M=N=2048, K=1024, batched over 8)
  gemm_bt<1><<<dim3(8, 8, 8), 512, 0, stream>>>(Qp, Kp, nullptr, S, scale,
                                                2048, 2048, 1024,
                                                (long)L * D, (long)L * D, (long)L * L);
  softmax_rows<<<16384, 256, 0, stream>>>(S);
  // out: O[b] = P[b] @ VT[b]^T  (M=2048, N=1024, K=2048, f32 out)
  gemm_bt<2><<<dim3(4, 8, 8), 512, 0, stream>>>(S, VT, nullptr, d_out, nullptr,
                                                2048, 1024, 2048,
                                                (long)L * L, (long)D * L, (long)L * D);
}

// Round 5
// 298.196 us; speedup vs baseline: 1.0386x; 1.0006x over previous
//
#include <hip/hip_runtime.h>

typedef __bf16 bf16;
typedef __attribute__((ext_vector_type(4))) __bf16 bf16x4;
typedef __attribute__((ext_vector_type(8))) __bf16 bf16x8;
typedef __attribute__((ext_vector_type(4))) float f32x4;

__device__ __forceinline__ void gload_lds16(const void* g, void* l) {
  __builtin_amdgcn_global_load_lds(
      (const __attribute__((address_space(1))) unsigned int*)(unsigned long long)g,
      (__attribute__((address_space(3))) unsigned int*)(unsigned long long)l,
      16, 0, 0);
}

// ---------------- cast fp32 -> bf16 (x4 vectorized) ----------------
__global__ void cast_f32_bf16(const float* __restrict__ in, bf16* __restrict__ out, int n4) {
  int i = blockIdx.x * blockDim.x + threadIdx.x;
  if (i >= n4) return;
  float4 v = reinterpret_cast<const float4*>(in)[i];
  bf16x4 o;
  o[0] = (bf16)v.x; o[1] = (bf16)v.y; o[2] = (bf16)v.z; o[3] = (bf16)v.w;
  reinterpret_cast<bf16x4*>(out)[i] = o;
}

// ------- transpose+cast: V (rows x cols, f32) -> VT (cols x rows, bf16), batched -------
__global__ void transpose_cast(const float* __restrict__ V, bf16* __restrict__ VT,
                               int rows, int cols) {
  __shared__ bf16 tile[64][65];
  const int b = blockIdx.z;
  const float* Vb = V + (long)b * rows * cols;
  bf16* VTb = VT + (long)b * rows * cols;
  const int d0 = blockIdx.x * 64;
  const int k0 = blockIdx.y * 64;
  const int t = threadIdx.x;
  const int r = t >> 4;
  const int c4 = (t & 15) * 4;
#pragma unroll
  for (int p = 0; p < 4; ++p) {
    float4 v = *reinterpret_cast<const float4*>(&Vb[(long)(k0 + p * 16 + r) * cols + d0 + c4]);
    tile[p * 16 + r][c4 + 0] = (bf16)v.x;
    tile[p * 16 + r][c4 + 1] = (bf16)v.y;
    tile[p * 16 + r][c4 + 2] = (bf16)v.z;
    tile[p * 16 + r][c4 + 3] = (bf16)v.w;
  }
  __syncthreads();
#pragma unroll
  for (int p = 0; p < 4; ++p) {
    const int dd = p * 16 + r;
    bf16x4 o;
    o[0] = tile[c4 + 0][dd];
    o[1] = tile[c4 + 1][dd];
    o[2] = tile[c4 + 2][dd];
    o[3] = tile[c4 + 3][dd];
    *reinterpret_cast<bf16x4*>(&VTb[(long)(d0 + dd) * rows + k0 + c4]) = o;
  }
}

// ---------------- in-place row softmax, row length 2048, bf16 ----------------
__global__ void softmax_rows(bf16* __restrict__ S) {
  const long row = blockIdx.x;
  bf16* p = S + row * 2048;
  const int t = threadIdx.x;
  const int wid = t >> 6;
  const int lane = t & 63;
  bf16x8 v = *reinterpret_cast<bf16x8*>(p + t * 8);
  float f[8];
  float m = -3.0e38f;
#pragma unroll
  for (int j = 0; j < 8; ++j) { f[j] = (float)v[j]; m = fmaxf(m, f[j]); }
#pragma unroll
  for (int off = 32; off >= 1; off >>= 1) m = fmaxf(m, __shfl_xor(m, off));
  __shared__ float redm[4], reds[4];
  if (lane == 0) redm[wid] = m;
  __syncthreads();
  m = fmaxf(fmaxf(redm[0], redm[1]), fmaxf(redm[2], redm[3]));
  float s = 0.f;
#pragma unroll
  for (int j = 0; j < 8; ++j) { f[j] = __expf(f[j] - m); s += f[j]; }
#pragma unroll
  for (int off = 32; off >= 1; off >>= 1) s += __shfl_xor(s, off);
  if (lane == 0) reds[wid] = s;
  __syncthreads();
  s = reds[0] + reds[1] + reds[2] + reds[3];
  const float inv = 1.0f / s;
  bf16x8 o;
#pragma unroll
  for (int j = 0; j < 8; ++j) o[j] = (bf16)(f[j] * inv);
  *reinterpret_cast<bf16x8*>(p + t * 8) = o;
}

// ---------------- B^T GEMM, 128x256 tile, BK=32, 2-blocks/CU TLP schedule --------------
// 512 threads = 8 waves (2 M x 4 N); wave owns 64x64 output (4x4 frags, acc[4][4]).
// LDS: 2 bufs x (A[128][32] + B[256][32]) bf16 = 48 KiB -> 2 blocks/CU co-resident
// (launch_bounds(512,4) caps regs at 128/wave: acc 64 + a/b 32 + addr fits).
// Cross-block anti-phase overlap hides the per-block ds_read->MFMA serialization that
// capped all 1-block/CU schedules at ~29% MfmaUtil (m97/m114 implicit-TLP mechanism).
// Per K-tile (T3 minimum-2-phase recipe): issue STAGE(kt+1 -> buf c^1) FIRST, then
// ds_reads of buf c, 16 MFMA, __syncthreads() (its vmcnt(0) drains a stage issued a
// full tile earlier ~ free; its barrier publishes LDS writes + read-completion).
// XOR chunk swizzle (R1/R4-verified, 0 conflicts): physical 16B-chunk = kc^((row>>1)&3),
// applied on global source (staging) and as a lane-constant read offset (both sides).
// MODE 0: bf16 out + bias (bz selects bias0/bias1); MODE 1: bf16 * (1/scale); MODE 2: f32.

#define STAGE(buf, ko)                          \
  {                                             \
    bf16* lA_ = ldsA + (buf) * 12288;           \
    bf16* lB_ = ldsB + (buf) * 12288;           \
    gload_lds16(gA + (ko), lA_);                \
    gload_lds16(gB + (ko), lB_);                \
    gload_lds16(gB + (ko) + rK128, lB_ + 4096); \
  }

#define LOADA(buf)                                                             \
  _Pragma("unroll") for (int m_ = 0; m_ < 4; ++m_)                             \
      a[m_] = *reinterpret_cast<const bf16x8*>(aB + (buf) * 12288 + m_ * 512);
#define LOADB(buf)                                                             \
  _Pragma("unroll") for (int n_ = 0; n_ < 4; ++n_)                             \
      b[n_] = *reinterpret_cast<const bf16x8*>(bB + (buf) * 12288 + n_ * 512);

#define MFMAP                                                                  \
  _Pragma("unroll") for (int m_ = 0; m_ < 4; ++m_)                             \
  _Pragma("unroll") for (int n_ = 0; n_ < 4; ++n_)                             \
      acc[m_][n_] = __builtin_amdgcn_mfma_f32_16x16x32_bf16(                   \
          a[m_], b[n_], acc[m_][n_], 0, 0, 0);

template <int MODE>
__global__ __launch_bounds__(512, 4)
void gemm_bt(const bf16* __restrict__ A, const bf16* __restrict__ Bm,
             const float* __restrict__ bias0, const float* __restrict__ bias1,
             void* __restrict__ Cvoid, const int* __restrict__ scale_ptr,
             int N, int K, long sA, long sB, long sC) {
  __shared__ bf16 lds[2][12288];  // per buf: A 128x32 (4096) + B 256x32 (8192) elems
  const int t = threadIdx.x;
  const int lane = t & 63;
  const int wid = t >> 6;   // 0..7
  const int wm = wid >> 2;  // 0..1
  const int wn = wid & 3;   // 0..3

  // XCD-aware bijective swizzle (all grids here have nwg % 8 == 0)
  const int gx = gridDim.x, gy = gridDim.y;
  const int nwg = gx * gy * gridDim.z;
  int id = blockIdx.x + gx * (blockIdx.y + gy * blockIdx.z);
  {
    const int cpx = nwg >> 3;
    id = (id & 7) * cpx + (id >> 3);
  }
  const int bx = id % gx;
  const int by = (id / gx) % gy;
  const int bz = id / (gx * gy);

  const bf16* Ab = A + (long)bz * sA;
  const bf16* Bb = Bm + (long)bz * sB;
  const int tile_m = by * 128;
  const int tile_n = bx * 256;

  // staging: A-tile [128][32] = 512 chunks (1 gload/thread); B-tile [256][32] = 1024
  // chunks (2 gloads/thread: rows srow, srow+128). chunk c: row=c>>2, kc=c&3;
  // source pre-swizzled: global kc = (t&3) ^ ((row>>1)&3); dest linear == row-major.
  const int srow = t >> 2;                              // 0..127
  const int soff = (((t & 3) ^ ((t >> 3) & 3)) << 3);   // swizzled elem offset in row
  const bf16* gA = Ab + (long)(tile_m + srow) * K + soff;
  const bf16* gB = Bb + (long)(tile_n + srow) * K + soff;
  const long rK128 = (long)K << 7;   // +128 rows
  bf16* const ldsA = &lds[0][0] + wid * 512;        // wave-uniform (+HW lane*16B)
  bf16* const ldsB = &lds[0][4096] + wid * 512;

  // fragment reads: row = base + frow (base % 16 == 0), logical k-chunk lane>>4;
  // physical chunk = (lane>>4) ^ ((frow>>1)&3) -> lane-constant byte offset.
  const int frow = lane & 15;
  const int pko = (((lane >> 4) ^ ((lane >> 1) & 3)) << 3);
  const bf16* aB = &lds[0][0] + (wm * 64 + frow) * 32 + pko;
  const bf16* bB = &lds[0][4096] + (wn * 64 + frow) * 32 + pko;

  bf16x8 a[4], b[4];
  f32x4 acc[4][4] = {};

  // prologue: stage tile 0 -> buf 0
  STAGE(0, 0)
  __syncthreads();

  const int NK = K >> 5;
  int c = 0;
  for (int kt = 0; kt < NK - 1; ++kt, c ^= 1) {
    STAGE(c ^ 1, (long)(kt + 1) << 5)   // issue next tile's 3 loads FIRST
    LOADB(c)
    LOADA(c)
    MFMAP
    __syncthreads();  // vmcnt(0)+lgkmcnt(0)+barrier: stage visible, reads done
  }
  // peeled last tile: compute only
  LOADB(c)
  LOADA(c)
  MFMAP

  float scl = 1.0f;
  if (MODE == 1) {
    const int iv = scale_ptr[0];
    const float fv = __int_as_float(iv);
    const float sv = (iv > 0 && iv < (1 << 20)) ? (float)iv : fv;
    scl = 1.0f / sv;
  }
  // C/D layout (verified m89/m91): col=lane&15, row=(lane>>4)*4+reg
  const int rb = tile_m + wm * 64 + ((lane >> 4) << 2);
  const int cb = tile_n + wn * 64 + (lane & 15);
  if (MODE == 2) {
    float* C = reinterpret_cast<float*>(Cvoid) + (long)bz * sC;
#pragma unroll
    for (int mf = 0; mf < 4; ++mf)
#pragma unroll
      for (int nf = 0; nf < 4; ++nf)
#pragma unroll
        for (int r = 0; r < 4; ++r)
          C[(long)(rb + mf * 16 + r) * N + (cb + nf * 16)] = acc[mf][nf][r];
  } else {
    bf16* C = reinterpret_cast<bf16*>(Cvoid) + (long)bz * sC;
    const float* bias = (MODE == 0) ? (bz ? bias1 : bias0) : nullptr;
#pragma unroll
    for (int nf = 0; nf < 4; ++nf) {
      const int col = cb + nf * 16;
      const float bv = (MODE == 0) ? bias[col] : 0.0f;
#pragma unroll
      for (int mf = 0; mf < 4; ++mf)
#pragma unroll
        for (int r = 0; r < 4; ++r)
          C[(long)(rb + mf * 16 + r) * N + col] = (bf16)(acc[mf][nf][r] * scl + bv);
    }
  }
}

extern "C" void kernel_launch(void* const* d_in, const int* in_sizes, int n_in,
                              void* d_out, int out_size, void* d_ws, size_t ws_size,
                              hipStream_t stream) {
  (void)in_sizes; (void)n_in; (void)out_size; (void)ws_size;
  const float* query = (const float*)d_in[0];
  const float* key   = (const float*)d_in[1];
  const float* value = (const float*)d_in[2];
  const float* Wq    = (const float*)d_in[3];
  const float* bq    = (const float*)d_in[4];
  const float* Wk    = (const float*)d_in[5];
  const float* bk    = (const float*)d_in[6];
  const int*   scale = (const int*)d_in[7];

  const int L = 2048, D = 1024;
  // ws layout (bytes):
  //   [0,   64M): q_cast(32M) + k_cast(32M), later reused as S/P (8*2048*2048 bf16 = 64M exactly)
  //   [64M, 96M): Qp   [96M,128M): Kp   [128M,160M): VT   [160M,162M): Wq_b  [162M,164M): Wk_b
  char* ws = (char*)d_ws;
  bf16* q_cast = (bf16*)ws;
  bf16* k_cast = q_cast + (long)16384 * 1024;
  bf16* S      = q_cast;
  bf16* Qp     = (bf16*)(ws + (size_t)67108864);
  bf16* Kp     = (bf16*)(ws + (size_t)100663296);
  bf16* VT     = (bf16*)(ws + (size_t)134217728);
  bf16* Wqb    = (bf16*)(ws + (size_t)167772160);
  bf16* Wkb    = (bf16*)(ws + (size_t)169869312);

  cast_f32_bf16<<<16384, 256, 0, stream>>>(query, q_cast, 4194304);
  cast_f32_bf16<<<16384, 256, 0, stream>>>(key,   k_cast, 4194304);
  cast_f32_bf16<<<1024,  256, 0, stream>>>(Wq, Wqb, 262144);
  cast_f32_bf16<<<1024,  256, 0, stream>>>(Wk, Wkb, 262144);
  transpose_cast<<<dim3(16, 32, 8), 256, 0, stream>>>(value, VT, 2048, 1024);

  // projections (fused Q+K in one launch; z=0 -> Q, z=1 -> K): M=16384, N=1024, K=1024
  gemm_bt<0><<<dim3(4, 128, 2), 512, 0, stream>>>(q_cast, Wqb, bq, bk, Qp, nullptr,
                                                  1024, 1024,
                                                  16777216L, 1048576L, 16777216L);
  // scores: S[b] = (Qp[b] @ Kp[b]^T) / scale   (M=N=2048, K=1024, batched over 8)
  gemm_bt<1><<<dim3(8, 16, 8), 512, 0, stream>>>(Qp, Kp, nullptr, nullptr, S, scale,
                                                 2048, 1024,
                                                 (long)L * D, (long)L * D, (long)L * L);
  softmax_rows<<<16384, 256, 0, stream>>>(S);
  // out: O[b] = P[b] @ VT[b]^T  (M=2048, N=1024, K=2048, f32 out)
  gemm_bt<2><<<dim3(4, 16, 8), 512, 0, stream>>>(S, VT, nullptr, nullptr, d_out, nullptr,
                                                 1024, 2048,
                                                 (long)L * L, (long)D * L, (long)L * D);
}